// Round 1
// baseline (197.346 us; speedup 1.0000x reference)
//
#include <hip/hip_runtime.h>
#include <math.h>

// Output: (B=4, S=8192, D=1024) fp32. pe[s][d] = sin(angle) for even d,
// cos(angle) for odd d, angle = (start_pos + s) * 10000^(-2d/1024).
// Value independent of batch -> compute once per (s,d), write 4 copies.
// Memory-bound: 128 MiB write, ~21 us floor at 6.3 TB/s.

#define PE_B 4
#define PE_S 8192
#define PE_D 1024

__global__ __launch_bounds__(256) void PositionalEmbedding_82042465288206_kernel(
    const int* __restrict__ start_pos_p, float* __restrict__ out)
{
    // One thread per float4 of the unique [S, D] plane: S*D/4 = 2M threads.
    const int i  = blockIdx.x * blockDim.x + threadIdx.x;
    const int s  = i >> 8;            // D/4 = 256 float4s per row
    const int d0 = (i & 255) << 2;    // starting d of this float4

    const float p = (float)(*start_pos_p + s);

    // inv_freq(d) = 10000^(-2d/1024) = exp2( d * (-2/1024)*log2(10000) )
    const float k = (-2.0f / 1024.0f) * 13.287712379549449f; // log2(10000)

    const float a0 = p * exp2f(k * (float)(d0 + 0));
    const float a1 = p * exp2f(k * (float)(d0 + 1));
    const float a2 = p * exp2f(k * (float)(d0 + 2));
    const float a3 = p * exp2f(k * (float)(d0 + 3));

    float4 v;
    v.x = sinf(a0);   // even d -> sin
    v.y = cosf(a1);   // odd d  -> cos
    v.z = sinf(a2);
    v.w = cosf(a3);

    // Broadcast the same float4 to all 4 batches (coalesced 16B stores).
    float4* o = (float4*)out;
    const size_t idx4    = (size_t)i;                    // (s*D + d0)/4 == i
    const size_t strideB = (size_t)PE_S * PE_D / 4;      // one batch, in float4s

    o[idx4]                = v;
    o[idx4 +     strideB]  = v;
    o[idx4 + 2 * strideB]  = v;
    o[idx4 + 3 * strideB]  = v;
}

extern "C" void kernel_launch(void* const* d_in, const int* in_sizes, int n_in,
                              void* d_out, int out_size, void* d_ws, size_t ws_size,
                              hipStream_t stream) {
    // d_in[0]: x (unused, shape-only), d_in[1]: start_pos (int scalar)
    const int* start_pos = (const int*)d_in[1];
    float* out = (float*)d_out;

    const int total4 = PE_S * PE_D / 4;       // 2,097,152 threads
    const int block  = 256;
    const int grid   = total4 / block;        // 8192 blocks

    PositionalEmbedding_82042465288206_kernel<<<grid, block, 0, stream>>>(start_pos, out);
}

// Round 2
// 197.035 us; speedup vs baseline: 1.0016x; 1.0016x over previous
//
#include <hip/hip_runtime.h>
#include <math.h>

// Output: (B=4, S=8192, D=1024) fp32. pe[s][d] = sin(a) for even d, cos(a) for
// odd d, a = (start_pos + s) * 10000^(-2d/1024). Batch-independent -> compute
// once per (s,d), write 4 copies. Write roofline: 128 MiB / ~6.5 TB/s ~= 20 us.
//
// R1 lesson: ocml sinf/cosf range reduction (args up to 8191 rad) made this
// VALU-bound at 197 us. Fix: work in REVOLUTIONS and use HW transcendentals:
//   angle_rev = p * 10000^(-2d/1024) / (2pi)   (one v_exp_f32)
//   t = fract(angle_rev); v_sin_f32(t) / v_cos_f32(t)
// __builtin_amdgcn_{sinf,cosf} map to v_sin/v_cos_f32 (revolution input, valid
// after fract). Error ~1e-3 rad from the p*w product rounding << 2e-2 threshold.

#define PE_B 4
#define PE_S 8192
#define PE_D 1024

__global__ __launch_bounds__(256) void PositionalEmbedding_82042465288206_kernel(
    const int* __restrict__ start_pos_p, float* __restrict__ out)
{
    // One thread per float4 of the unique [S, D] plane: S*D/4 = 2M threads.
    const int i  = blockIdx.x * blockDim.x + threadIdx.x;
    const int s  = i >> 8;            // D/4 = 256 float4s per row
    const int d0 = (i & 255) << 2;    // starting d of this float4

    const float p = (float)(*start_pos_p + s);

    // w_rev(d) = 10000^(-2d/1024) / (2pi) = exp2(k*d + c)
    const float k = (-2.0f / 1024.0f) * 13.287712379549449f;  // -(2/1024)*log2(1e4)
    const float c = -2.6514961294723187f;                     // -log2(2*pi)

    const float w0 = __builtin_amdgcn_exp2f(k * (float)(d0 + 0) + c);
    const float w1 = __builtin_amdgcn_exp2f(k * (float)(d0 + 1) + c);
    const float w2 = __builtin_amdgcn_exp2f(k * (float)(d0 + 2) + c);
    const float w3 = __builtin_amdgcn_exp2f(k * (float)(d0 + 3) + c);

    float t0 = p * w0;  t0 -= floorf(t0);   // v_fract
    float t1 = p * w1;  t1 -= floorf(t1);
    float t2 = p * w2;  t2 -= floorf(t2);
    float t3 = p * w3;  t3 -= floorf(t3);

    float4 v;
    v.x = __builtin_amdgcn_sinf(t0);   // even d -> sin(2*pi*t)
    v.y = __builtin_amdgcn_cosf(t1);   // odd d  -> cos(2*pi*t)
    v.z = __builtin_amdgcn_sinf(t2);
    v.w = __builtin_amdgcn_cosf(t3);

    // Broadcast the same float4 to all 4 batches (coalesced 16B stores).
    float4* o = (float4*)out;
    const size_t idx4    = (size_t)i;                    // (s*D + d0)/4 == i
    const size_t strideB = (size_t)PE_S * PE_D / 4;      // one batch, in float4s

    o[idx4]                = v;
    o[idx4 +     strideB]  = v;
    o[idx4 + 2 * strideB]  = v;
    o[idx4 + 3 * strideB]  = v;
}

extern "C" void kernel_launch(void* const* d_in, const int* in_sizes, int n_in,
                              void* d_out, int out_size, void* d_ws, size_t ws_size,
                              hipStream_t stream) {
    // d_in[0]: x (unused, shape-only), d_in[1]: start_pos (int scalar)
    const int* start_pos = (const int*)d_in[1];
    float* out = (float*)d_out;

    const int total4 = PE_S * PE_D / 4;       // 2,097,152 threads
    const int block  = 256;
    const int grid   = total4 / block;        // 8192 blocks

    PositionalEmbedding_82042465288206_kernel<<<grid, block, 0, stream>>>(start_pos, out);
}